// Round 2
// baseline (819.529 us; speedup 1.0000x reference)
//
#include <hip/hip_runtime.h>
#include <cstdint>
#include <cstddef>

#define N_NODES 100000
#define N_EDGES 1600000
#define D 128
#define NLAYERS 3

// ---------------- setup kernels ----------------

__global__ void count_deg_kernel(const int* __restrict__ col, int* __restrict__ deg, int e) {
    int i = blockIdx.x * 256 + threadIdx.x;
    if (i < e) atomicAdd(&deg[col[i]], 1);
}

__global__ void dinv_kernel(const int* __restrict__ deg, float* __restrict__ dinv, int n) {
    int i = blockIdx.x * 256 + threadIdx.x;
    if (i < n) dinv[i] = rsqrtf((float)(deg[i] + 1));  // +1 = self loop; always > 0
}

// exclusive scan, step 1: per-256-block exclusive scan + block sums
__global__ void scan1_kernel(const int* __restrict__ deg, int* __restrict__ excl,
                             int* __restrict__ bsums, int n) {
    __shared__ int tmp[256];
    int t = threadIdx.x;
    int g = blockIdx.x * 256 + t;
    int v = (g < n) ? deg[g] : 0;
    tmp[t] = v;
    __syncthreads();
    for (int off = 1; off < 256; off <<= 1) {
        int x = (t >= off) ? tmp[t - off] : 0;
        __syncthreads();
        tmp[t] += x;
        __syncthreads();
    }
    if (g < n) excl[g] = tmp[t] - v;              // exclusive within block
    if (t == 255) bsums[blockIdx.x] = tmp[255];   // block total
}

// step 2: single-block exclusive scan over block sums (nb <= 512)
__global__ void scan2_kernel(int* __restrict__ bsums, int nb) {
    __shared__ int tmp[512];
    int t = threadIdx.x;
    int v = (t < nb) ? bsums[t] : 0;
    tmp[t] = v;
    __syncthreads();
    for (int off = 1; off < 512; off <<= 1) {
        int x = (t >= off) ? tmp[t - off] : 0;
        __syncthreads();
        tmp[t] += x;
        __syncthreads();
    }
    if (t < nb) bsums[t] = tmp[t] - v;            // exclusive
}

// step 3: combine -> offsets, init cursors, write sentinel
__global__ void scan3_kernel(int* __restrict__ offsets, const int* __restrict__ bsums,
                             int* __restrict__ cursor, int n, int e) {
    int g = blockIdx.x * 256 + threadIdx.x;
    if (g < n) {
        int o = offsets[g] + bsums[g >> 8];
        offsets[g] = o;
        cursor[g] = o;
    }
    if (g == 0) offsets[n] = e;
}

// Single 4B scatter per edge (src only; weight recomputed in agg from dinv).
__global__ void fill_csr_kernel(const int* __restrict__ row, const int* __restrict__ col,
                                int* __restrict__ cursor, int* __restrict__ src, int e) {
    int i = blockIdx.x * 256 + threadIdx.x;
    if (i < e) {
        int r = row[i], c = col[i];
        int pos = atomicAdd(&cursor[c], 1);
        src[pos] = r;
    }
}

// ---------------- per-layer kernels ----------------

// One 64-thread block per node; each thread owns a float2 feature pair.
// out[v] = dinv[v] * ( dinv[v]*x[v] + sum_e dinv[src_e]*x[src_e] )
__global__ void agg_kernel(const float* __restrict__ x, const int* __restrict__ offs,
                           const int* __restrict__ src, const float* __restrict__ dinv,
                           float* __restrict__ out) {
    int v = blockIdx.x;
    int f = threadIdx.x;  // 0..63
    const float2* x2 = (const float2*)x;
    float dv = dinv[v];
    float2 xv = x2[(size_t)v * 64 + f];
    float ax = dv * xv.x;
    float ay = dv * xv.y;
    int i = offs[v], s1 = offs[v + 1];
    for (; i + 3 < s1; i += 4) {
        int sA = src[i], sB = src[i + 1], sC = src[i + 2], sD = src[i + 3];
        float wA = dinv[sA], wB = dinv[sB], wC = dinv[sC], wD = dinv[sD];
        float2 xA = x2[(size_t)sA * 64 + f];
        float2 xB = x2[(size_t)sB * 64 + f];
        float2 xC = x2[(size_t)sC * 64 + f];
        float2 xD = x2[(size_t)sD * 64 + f];
        ax += xA.x * wA + xB.x * wB + xC.x * wC + xD.x * wD;
        ay += xA.y * wA + xB.y * wB + xC.y * wC + xD.y * wD;
    }
    for (; i < s1; i++) {
        int sA = src[i];
        float wA = dinv[sA];
        float2 xA = x2[(size_t)sA * 64 + f];
        ax += xA.x * wA;
        ay += xA.y * wA;
    }
    float2 r;
    r.x = dv * ax;
    r.y = dv * ay;
    ((float2*)out)[(size_t)v * 64 + f] = r;
}

// out[M x 128] = relu(A[M x 128] @ W[128 x 128] + bias), 32 rows per block,
// W staged in LDS (64 KB), A-tile 16 KB, 4x4 register blocking.
__global__ __launch_bounds__(256, 2) void gemm_bias_relu_kernel(
    const float* __restrict__ A, const float* __restrict__ W,
    const float* __restrict__ bias, float* __restrict__ out, int M) {
    __shared__ float sW[128 * 128];  // 64 KB
    __shared__ float sX[32 * 128];   // 16 KB; reads are wave-broadcast, no pad needed
    int t = threadIdx.x;
    int tx = t & 31;   // 32 col-groups of 4
    int ty = t >> 5;   // 8 row-groups of 4
    int row0 = blockIdx.x * 32;

    const float4* W4 = (const float4*)W;
    float4* sW4 = (float4*)sW;
#pragma unroll
    for (int i = 0; i < 16; i++) sW4[t + 256 * i] = W4[t + 256 * i];

    const float4* A4 = (const float4*)A;
    float4* sX4 = (float4*)sX;
#pragma unroll
    for (int i = 0; i < 4; i++) {
        int c = t + 256 * i;
        int r = c >> 5, kc = c & 31;
        sX4[r * 32 + kc] = A4[(size_t)(row0 + r) * 32 + kc];
    }
    __syncthreads();

    float acc[4][4] = {};
#pragma unroll 8
    for (int k = 0; k < 128; k++) {
        float a0 = sX[(ty * 4 + 0) * 128 + k];
        float a1 = sX[(ty * 4 + 1) * 128 + k];
        float a2 = sX[(ty * 4 + 2) * 128 + k];
        float a3 = sX[(ty * 4 + 3) * 128 + k];
        float4 bv = *(const float4*)&sW[k * 128 + tx * 4];
        acc[0][0] += a0 * bv.x; acc[0][1] += a0 * bv.y; acc[0][2] += a0 * bv.z; acc[0][3] += a0 * bv.w;
        acc[1][0] += a1 * bv.x; acc[1][1] += a1 * bv.y; acc[1][2] += a1 * bv.z; acc[1][3] += a1 * bv.w;
        acc[2][0] += a2 * bv.x; acc[2][1] += a2 * bv.y; acc[2][2] += a2 * bv.z; acc[2][3] += a2 * bv.w;
        acc[3][0] += a3 * bv.x; acc[3][1] += a3 * bv.y; acc[3][2] += a3 * bv.z; acc[3][3] += a3 * bv.w;
    }

    float4 bb = ((const float4*)bias)[tx];
#pragma unroll
    for (int r = 0; r < 4; r++) {
        float4 o;
        o.x = fmaxf(acc[r][0] + bb.x, 0.0f);
        o.y = fmaxf(acc[r][1] + bb.y, 0.0f);
        o.z = fmaxf(acc[r][2] + bb.z, 0.0f);
        o.w = fmaxf(acc[r][3] + bb.w, 0.0f);
        ((float4*)out)[(size_t)(row0 + ty * 4 + r) * 32 + tx] = o;
    }
}

// ---------------- launch ----------------

extern "C" void kernel_launch(void* const* d_in, const int* in_sizes, int n_in,
                              void* d_out, int out_size, void* d_ws, size_t ws_size,
                              hipStream_t stream) {
    const int* edge = (const int*)d_in[0];   // [2, E] int32
    const float* emb = (const float*)d_in[1];
    const float* Ws = (const float*)d_in[2]; // [L, D, D]
    const float* bs = (const float*)d_in[3]; // [L, D]
    float* out = (float*)d_out;

    const int n = N_NODES, e = N_EDGES;
    const int* row = edge;       // sources
    const int* col = edge + e;   // targets

    char* p = (char*)d_ws;
    float* aggbuf = (float*)p;  p += (size_t)n * D * 4;       // 51.2 MB
    int* csr_src  = (int*)p;    p += (size_t)e * 4;           // 6.4 MB
    float* dinv   = (float*)p;  p += (size_t)n * 4;
    int* deg      = (int*)p;    p += (size_t)n * 4;
    int* offsets  = (int*)p;    p += (size_t)(n + 1) * 4;
    int* cursor   = (int*)p;    p += (size_t)n * 4;
    int* bsums    = (int*)p;    p += 4096;

    int nblk = (n + 255) / 256;   // 391
    int eblk = (e + 255) / 256;   // 6250

    hipMemsetAsync(deg, 0, (size_t)n * 4, stream);
    count_deg_kernel<<<eblk, 256, 0, stream>>>(col, deg, e);
    dinv_kernel<<<nblk, 256, 0, stream>>>(deg, dinv, n);
    scan1_kernel<<<nblk, 256, 0, stream>>>(deg, offsets, bsums, n);
    scan2_kernel<<<1, 512, 0, stream>>>(bsums, nblk);
    scan3_kernel<<<nblk, 256, 0, stream>>>(offsets, bsums, cursor, n, e);
    fill_csr_kernel<<<eblk, 256, 0, stream>>>(row, col, cursor, csr_src, e);

    const float* x = emb;
    for (int l = 0; l < NLAYERS; l++) {
        agg_kernel<<<n, 64, 0, stream>>>(x, offsets, csr_src, dinv, aggbuf);
        gemm_bias_relu_kernel<<<n / 32, 256, 0, stream>>>(
            aggbuf, Ws + (size_t)l * D * D, bs + (size_t)l * D, out, n);
        x = out;
    }
}

// Round 3
// 767.900 us; speedup vs baseline: 1.0672x; 1.0672x over previous
//
#include <hip/hip_runtime.h>
#include <cstdint>
#include <cstddef>

#define N_NODES 100000
#define N_EDGES 1600000
#define D 128
#define NLAYERS 3
#define NB 3125      // buckets of 32 nodes: 100000/32
#define CAP 1024     // bucket capacity; mean 512, std 22.6 -> 22 sigma margin

// ---------------- CSR build via bucket binning ----------------

// Bin edges by col>>5. One global atomic per edge on a 12.5 KB counter array;
// payload packed (row<<5)|(col&31) appended into the bucket region.
__global__ void bin_kernel(const int* __restrict__ row, const int* __restrict__ col,
                           int* __restrict__ bcnt, unsigned* __restrict__ bucketbuf, int e) {
    int i = blockIdx.x * 256 + threadIdx.x;
    if (i < e) {
        int r = row[i], c = col[i];
        int b = c >> 5;
        int pos = atomicAdd(&bcnt[b], 1);
        if (pos < CAP) bucketbuf[b * CAP + pos] = ((unsigned)r << 5) | (unsigned)(c & 31);
    }
}

// Single-block exclusive scan over the 3125 bucket counts.
__global__ void bscan_kernel(const int* __restrict__ bcnt, int* __restrict__ bstart, int nb) {
    __shared__ int lsum[1024];
    int t = threadIdx.x;
    int vals[4];
    int v0 = 0;
#pragma unroll
    for (int j = 0; j < 4; j++) {
        int idx = t * 4 + j;
        int c = (idx < nb) ? bcnt[idx] : 0;
        vals[j] = c;
        v0 += c;
    }
    lsum[t] = v0;
    __syncthreads();
    for (int off = 1; off < 1024; off <<= 1) {
        int x = (t >= off) ? lsum[t - off] : 0;
        __syncthreads();
        lsum[t] += x;
        __syncthreads();
    }
    int base = lsum[t] - v0;  // exclusive
#pragma unroll
    for (int j = 0; j < 4; j++) {
        int idx = t * 4 + j;
        if (idx < nb) {
            bstart[idx] = base;
            base += vals[j];
        }
    }
}

// One block per bucket: LDS histogram of 32 local cols -> per-node offsets,
// dinv, and localized CSR scatter (contiguous ~2KB range, LDS cursors).
__global__ void fill2_kernel(const unsigned* __restrict__ bucketbuf, const int* __restrict__ bcnt,
                             const int* __restrict__ bstart, int* __restrict__ offsets,
                             float* __restrict__ dinv, int* __restrict__ src, int n, int e) {
    __shared__ unsigned ent[CAP];
    __shared__ int hist[32];
    __shared__ int cur[32];
    __shared__ int loff[32];
    int b = blockIdx.x, t = threadIdx.x;
    int cnt = bcnt[b];
    if (cnt > CAP) cnt = CAP;
    if (t < 32) hist[t] = 0;
    __syncthreads();
    for (int i = t; i < cnt; i += 256) {
        unsigned v = bucketbuf[b * CAP + i];
        ent[i] = v;
        atomicAdd(&hist[v & 31], 1);
    }
    __syncthreads();
    if (t == 0) {
        int run = bstart[b];
#pragma unroll
        for (int j = 0; j < 32; j++) {
            loff[j] = run;
            run += hist[j];
        }
    }
    __syncthreads();
    if (t < 32) {
        int node = b * 32 + t;
        int o = loff[t];
        offsets[node] = o;
        cur[t] = o;
        dinv[node] = rsqrtf((float)(hist[t] + 1));  // +1 self loop
    }
    if (b == 0 && t == 0) offsets[n] = e;
    __syncthreads();
    for (int i = t; i < cnt; i += 256) {
        unsigned v = ent[i];
        int pos = atomicAdd(&cur[v & 31], 1);
        src[pos] = (int)(v >> 5);
    }
}

// ---------------- per-layer kernels ----------------

// One 64-thread block per node; each thread owns a float2 feature pair.
// out[v] = dinv[v] * ( dinv[v]*x[v] + sum_e dinv[src_e]*x[src_e] )
__global__ void agg_kernel(const float* __restrict__ x, const int* __restrict__ offs,
                           const int* __restrict__ src, const float* __restrict__ dinv,
                           float* __restrict__ out) {
    int v = blockIdx.x;
    int f = threadIdx.x;  // 0..63
    const float2* x2 = (const float2*)x;
    float dv = dinv[v];
    float2 xv = x2[(size_t)v * 64 + f];
    float ax = dv * xv.x;
    float ay = dv * xv.y;
    int i = offs[v], s1 = offs[v + 1];
    for (; i + 3 < s1; i += 4) {
        int sA = src[i], sB = src[i + 1], sC = src[i + 2], sD = src[i + 3];
        float wA = dinv[sA], wB = dinv[sB], wC = dinv[sC], wD = dinv[sD];
        float2 xA = x2[(size_t)sA * 64 + f];
        float2 xB = x2[(size_t)sB * 64 + f];
        float2 xC = x2[(size_t)sC * 64 + f];
        float2 xD = x2[(size_t)sD * 64 + f];
        ax += xA.x * wA + xB.x * wB + xC.x * wC + xD.x * wD;
        ay += xA.y * wA + xB.y * wB + xC.y * wC + xD.y * wD;
    }
    for (; i < s1; i++) {
        int sA = src[i];
        float wA = dinv[sA];
        float2 xA = x2[(size_t)sA * 64 + f];
        ax += xA.x * wA;
        ay += xA.y * wA;
    }
    float2 r;
    r.x = dv * ax;
    r.y = dv * ay;
    ((float2*)out)[(size_t)v * 64 + f] = r;
}

// out[M x 128] = relu(A[M x 128] @ W[128 x 128] + bias), 32 rows per block,
// W staged in LDS (64 KB), A-tile 16 KB, 4x4 register blocking.
__global__ __launch_bounds__(256, 2) void gemm_bias_relu_kernel(
    const float* __restrict__ A, const float* __restrict__ W,
    const float* __restrict__ bias, float* __restrict__ out, int M) {
    __shared__ float sW[128 * 128];  // 64 KB
    __shared__ float sX[32 * 128];   // 16 KB; reads are wave-broadcast, no pad needed
    int t = threadIdx.x;
    int tx = t & 31;   // 32 col-groups of 4
    int ty = t >> 5;   // 8 row-groups of 4
    int row0 = blockIdx.x * 32;

    const float4* W4 = (const float4*)W;
    float4* sW4 = (float4*)sW;
#pragma unroll
    for (int i = 0; i < 16; i++) sW4[t + 256 * i] = W4[t + 256 * i];

    const float4* A4 = (const float4*)A;
    float4* sX4 = (float4*)sX;
#pragma unroll
    for (int i = 0; i < 4; i++) {
        int c = t + 256 * i;
        int r = c >> 5, kc = c & 31;
        sX4[r * 32 + kc] = A4[(size_t)(row0 + r) * 32 + kc];
    }
    __syncthreads();

    float acc[4][4] = {};
#pragma unroll 8
    for (int k = 0; k < 128; k++) {
        float a0 = sX[(ty * 4 + 0) * 128 + k];
        float a1 = sX[(ty * 4 + 1) * 128 + k];
        float a2 = sX[(ty * 4 + 2) * 128 + k];
        float a3 = sX[(ty * 4 + 3) * 128 + k];
        float4 bv = *(const float4*)&sW[k * 128 + tx * 4];
        acc[0][0] += a0 * bv.x; acc[0][1] += a0 * bv.y; acc[0][2] += a0 * bv.z; acc[0][3] += a0 * bv.w;
        acc[1][0] += a1 * bv.x; acc[1][1] += a1 * bv.y; acc[1][2] += a1 * bv.z; acc[1][3] += a1 * bv.w;
        acc[2][0] += a2 * bv.x; acc[2][1] += a2 * bv.y; acc[2][2] += a2 * bv.z; acc[2][3] += a2 * bv.w;
        acc[3][0] += a3 * bv.x; acc[3][1] += a3 * bv.y; acc[3][2] += a3 * bv.z; acc[3][3] += a3 * bv.w;
    }

    float4 bb = ((const float4*)bias)[tx];
#pragma unroll
    for (int r = 0; r < 4; r++) {
        float4 o;
        o.x = fmaxf(acc[r][0] + bb.x, 0.0f);
        o.y = fmaxf(acc[r][1] + bb.y, 0.0f);
        o.z = fmaxf(acc[r][2] + bb.z, 0.0f);
        o.w = fmaxf(acc[r][3] + bb.w, 0.0f);
        ((float4*)out)[(size_t)(row0 + ty * 4 + r) * 32 + tx] = o;
    }
}

// ---------------- launch ----------------

extern "C" void kernel_launch(void* const* d_in, const int* in_sizes, int n_in,
                              void* d_out, int out_size, void* d_ws, size_t ws_size,
                              hipStream_t stream) {
    const int* edge = (const int*)d_in[0];   // [2, E] int32
    const float* emb = (const float*)d_in[1];
    const float* Ws = (const float*)d_in[2]; // [L, D, D]
    const float* bs = (const float*)d_in[3]; // [L, D]
    float* out = (float*)d_out;

    const int n = N_NODES, e = N_EDGES;
    const int* row = edge;       // sources
    const int* col = edge + e;   // targets

    char* p = (char*)d_ws;
    float* aggbuf = (float*)p;
    unsigned* bucketbuf = (unsigned*)p;  // aliases aggbuf: dead before first agg write
    p += (size_t)n * D * 4;              // 51.2 MB
    int* csr_src  = (int*)p;    p += (size_t)e * 4;           // 6.4 MB
    float* dinv   = (float*)p;  p += (size_t)n * 4;
    int* offsets  = (int*)p;    p += (size_t)(n + 1) * 4;
    int* bcnt     = (int*)p;    p += (size_t)NB * 4;
    int* bstart   = (int*)p;    p += (size_t)NB * 4;

    int eblk = (e + 255) / 256;   // 6250

    hipMemsetAsync(bcnt, 0, (size_t)NB * 4, stream);
    bin_kernel<<<eblk, 256, 0, stream>>>(row, col, bcnt, bucketbuf, e);
    bscan_kernel<<<1, 1024, 0, stream>>>(bcnt, bstart, NB);
    fill2_kernel<<<NB, 256, 0, stream>>>(bucketbuf, bcnt, bstart, offsets, dinv, csr_src, n, e);

    const float* x = emb;
    for (int l = 0; l < NLAYERS; l++) {
        agg_kernel<<<n, 64, 0, stream>>>(x, offsets, csr_src, dinv, aggbuf);
        gemm_bias_relu_kernel<<<n / 32, 256, 0, stream>>>(
            aggbuf, Ws + (size_t)l * D * D, bs + (size_t)l * D, out, n);
        x = out;
    }
}

// Round 4
// 581.203 us; speedup vs baseline: 1.4101x; 1.3212x over previous
//
#include <hip/hip_runtime.h>
#include <hip/hip_fp16.h>
#include <cstdint>
#include <cstddef>

#define N_NODES 100000
#define N_EDGES 1600000
#define D 128
#define NLAYERS 3
#define NB 3125      // buckets of 32 nodes: 100000/32
#define CAP 1024     // bucket capacity; mean 512, std 22.6 -> 22 sigma margin
#define CSTRIDE 16   // bcnt padded: one counter per 64B line

// ---------------- CSR build via bucket binning ----------------

// Bin edges by col>>5. Padded counters: one per cache line (same-line atomic
// serialization was the R3 bottleneck: 8200 ops/line x ~42cyc = 143us).
__global__ void bin_kernel(const int* __restrict__ row, const int* __restrict__ col,
                           int* __restrict__ bcnt, unsigned* __restrict__ bucketbuf, int e) {
    int i = blockIdx.x * 256 + threadIdx.x;
    if (i < e) {
        int r = row[i], c = col[i];
        int b = c >> 5;
        int pos = atomicAdd(&bcnt[b * CSTRIDE], 1);
        if (pos < CAP) bucketbuf[b * CAP + pos] = ((unsigned)r << 5) | (unsigned)(c & 31);
    }
}

// Single-block exclusive scan over the 3125 bucket counts.
__global__ void bscan_kernel(const int* __restrict__ bcnt, int* __restrict__ bstart, int nb) {
    __shared__ int lsum[1024];
    int t = threadIdx.x;
    int vals[4];
    int v0 = 0;
#pragma unroll
    for (int j = 0; j < 4; j++) {
        int idx = t * 4 + j;
        int c = (idx < nb) ? bcnt[idx * CSTRIDE] : 0;
        vals[j] = c;
        v0 += c;
    }
    lsum[t] = v0;
    __syncthreads();
    for (int off = 1; off < 1024; off <<= 1) {
        int x = (t >= off) ? lsum[t - off] : 0;
        __syncthreads();
        lsum[t] += x;
        __syncthreads();
    }
    int base = lsum[t] - v0;  // exclusive
#pragma unroll
    for (int j = 0; j < 4; j++) {
        int idx = t * 4 + j;
        if (idx < nb) {
            bstart[idx] = base;
            base += vals[j];
        }
    }
}

// One block per bucket: LDS histogram of 32 local cols -> per-node offsets,
// dinv, and localized CSR scatter (contiguous ~2KB range, LDS cursors).
__global__ void fill2_kernel(const unsigned* __restrict__ bucketbuf, const int* __restrict__ bcnt,
                             const int* __restrict__ bstart, int* __restrict__ offsets,
                             float* __restrict__ dinv, int* __restrict__ src, int n, int e) {
    __shared__ unsigned ent[CAP];
    __shared__ int hist[32];
    __shared__ int cur[32];
    __shared__ int loff[32];
    int b = blockIdx.x, t = threadIdx.x;
    int cnt = bcnt[b * CSTRIDE];
    if (cnt > CAP) cnt = CAP;
    if (t < 32) hist[t] = 0;
    __syncthreads();
    for (int i = t; i < cnt; i += 256) {
        unsigned v = bucketbuf[b * CAP + i];
        ent[i] = v;
        atomicAdd(&hist[v & 31], 1);
    }
    __syncthreads();
    if (t == 0) {
        int run = bstart[b];
#pragma unroll
        for (int j = 0; j < 32; j++) {
            loff[j] = run;
            run += hist[j];
        }
    }
    __syncthreads();
    if (t < 32) {
        int node = b * 32 + t;
        int o = loff[t];
        offsets[node] = o;
        cur[t] = o;
        dinv[node] = rsqrtf((float)(hist[t] + 1));  // +1 self loop
    }
    if (b == 0 && t == 0) offsets[n] = e;
    __syncthreads();
    for (int i = t; i < cnt; i += 256) {
        unsigned v = ent[i];
        int pos = atomicAdd(&cur[v & 31], 1);
        src[pos] = (int)(v >> 5);
    }
}

// ---------------- per-layer kernels ----------------

// Cast fp32 features -> fp16 (halves gather traffic in agg).
__global__ void cast_kernel(const float2* __restrict__ in, __half2* __restrict__ out, int n2) {
    int i = blockIdx.x * 256 + threadIdx.x;
    if (i < n2) {
        float2 v = in[i];
        out[i] = __floats2half2_rn(v.x, v.y);
    }
}

// One 64-thread block per node; each thread owns a half2 feature pair.
// out[v] = dinv[v] * ( dinv[v]*x[v] + sum_e dinv[src_e]*x[src_e] ), fp32 accum.
__global__ void agg_kernel(const __half2* __restrict__ xh, const int* __restrict__ offs,
                           const int* __restrict__ src, const float* __restrict__ dinv,
                           float* __restrict__ out) {
    int v = blockIdx.x;
    int f = threadIdx.x;  // 0..63
    float dv = dinv[v];
    float2 xv = __half22float2(xh[(size_t)v * 64 + f]);
    float ax = dv * xv.x;
    float ay = dv * xv.y;
    int i = offs[v], s1 = offs[v + 1];
    for (; i + 3 < s1; i += 4) {
        int sA = src[i], sB = src[i + 1], sC = src[i + 2], sD = src[i + 3];
        float wA = dinv[sA], wB = dinv[sB], wC = dinv[sC], wD = dinv[sD];
        float2 xA = __half22float2(xh[(size_t)sA * 64 + f]);
        float2 xB = __half22float2(xh[(size_t)sB * 64 + f]);
        float2 xC = __half22float2(xh[(size_t)sC * 64 + f]);
        float2 xD = __half22float2(xh[(size_t)sD * 64 + f]);
        ax += xA.x * wA + xB.x * wB + xC.x * wC + xD.x * wD;
        ay += xA.y * wA + xB.y * wB + xC.y * wC + xD.y * wD;
    }
    for (; i < s1; i++) {
        int sA = src[i];
        float wA = dinv[sA];
        float2 xA = __half22float2(xh[(size_t)sA * 64 + f]);
        ax += xA.x * wA;
        ay += xA.y * wA;
    }
    float2 r;
    r.x = dv * ax;
    r.y = dv * ay;
    ((float2*)out)[(size_t)v * 64 + f] = r;
}

// out[M x 128] = relu(A[M x 128] @ W[128 x 128] + bias), 32 rows per block,
// W staged in LDS (64 KB), k-vectorized float4 inner loop (4 FLOP/LDS-byte).
// Optionally also writes an fp16 copy for the next layer's gather.
__global__ __launch_bounds__(256, 2) void gemm_bias_relu_kernel(
    const float* __restrict__ A, const float* __restrict__ W,
    const float* __restrict__ bias, float* __restrict__ out,
    __half2* __restrict__ xh_out, int write_h) {
    __shared__ float sW[128 * 128];  // 64 KB
    __shared__ float sX[32 * 128];   // 16 KB
    int t = threadIdx.x;
    int tx = t & 31;   // 32 col-groups of 4
    int ty = t >> 5;   // 8 row-groups of 4
    int row0 = blockIdx.x * 32;

    const float4* W4 = (const float4*)W;
    float4* sW4 = (float4*)sW;
#pragma unroll
    for (int i = 0; i < 16; i++) sW4[t + 256 * i] = W4[t + 256 * i];

    const float4* A4 = (const float4*)A;
    float4* sX4 = (float4*)sX;
#pragma unroll
    for (int i = 0; i < 4; i++) {
        int c = t + 256 * i;
        int r = c >> 5, kc = c & 31;
        sX4[r * 32 + kc] = A4[(size_t)(row0 + r) * 32 + kc];
    }
    __syncthreads();

    float4 acc[4];
#pragma unroll
    for (int r = 0; r < 4; r++) acc[r] = make_float4(0.f, 0.f, 0.f, 0.f);

#define FMA4(a, s, b) a.x += (s) * (b).x; a.y += (s) * (b).y; a.z += (s) * (b).z; a.w += (s) * (b).w;
#pragma unroll 4
    for (int k0 = 0; k0 < 128; k0 += 4) {
        float4 b0 = *(const float4*)&sW[(k0 + 0) * 128 + tx * 4];
        float4 b1 = *(const float4*)&sW[(k0 + 1) * 128 + tx * 4];
        float4 b2 = *(const float4*)&sW[(k0 + 2) * 128 + tx * 4];
        float4 b3 = *(const float4*)&sW[(k0 + 3) * 128 + tx * 4];
#pragma unroll
        for (int r = 0; r < 4; r++) {
            float4 a = *(const float4*)&sX[(ty * 4 + r) * 128 + k0];
            FMA4(acc[r], a.x, b0)
            FMA4(acc[r], a.y, b1)
            FMA4(acc[r], a.z, b2)
            FMA4(acc[r], a.w, b3)
        }
    }
#undef FMA4

    float4 bb = ((const float4*)bias)[tx];
#pragma unroll
    for (int r = 0; r < 4; r++) {
        float4 o;
        o.x = fmaxf(acc[r].x + bb.x, 0.0f);
        o.y = fmaxf(acc[r].y + bb.y, 0.0f);
        o.z = fmaxf(acc[r].z + bb.z, 0.0f);
        o.w = fmaxf(acc[r].w + bb.w, 0.0f);
        size_t rowi = (size_t)(row0 + ty * 4 + r);
        ((float4*)out)[rowi * 32 + tx] = o;
        if (write_h) {
            xh_out[rowi * 64 + tx * 2] = __floats2half2_rn(o.x, o.y);
            xh_out[rowi * 64 + tx * 2 + 1] = __floats2half2_rn(o.z, o.w);
        }
    }
}

// ---------------- launch ----------------

extern "C" void kernel_launch(void* const* d_in, const int* in_sizes, int n_in,
                              void* d_out, int out_size, void* d_ws, size_t ws_size,
                              hipStream_t stream) {
    const int* edge = (const int*)d_in[0];   // [2, E] int32
    const float* emb = (const float*)d_in[1];
    const float* Ws = (const float*)d_in[2]; // [L, D, D]
    const float* bs = (const float*)d_in[3]; // [L, D]
    float* out = (float*)d_out;

    const int n = N_NODES, e = N_EDGES;
    const int* row = edge;       // sources
    const int* col = edge + e;   // targets

    char* p = (char*)d_ws;
    float* aggbuf = (float*)p;  p += (size_t)n * D * 4;       // 51.2 MB
    __half2* xh = (__half2*)p;                                // 25.6 MB
    unsigned* bucketbuf = (unsigned*)p;  // aliases xh: bucketbuf dead before cast runs
    p += (size_t)n * D * 2;
    int* csr_src  = (int*)p;    p += (size_t)e * 4;           // 6.4 MB
    float* dinv   = (float*)p;  p += (size_t)n * 4;
    int* offsets  = (int*)p;    p += (size_t)(n + 1) * 4;
    int* bcnt     = (int*)p;    p += (size_t)NB * CSTRIDE * 4; // 200 KB padded
    int* bstart   = (int*)p;    p += (size_t)NB * 4;

    int eblk = (e + 255) / 256;   // 6250

    hipMemsetAsync(bcnt, 0, (size_t)NB * CSTRIDE * 4, stream);
    bin_kernel<<<eblk, 256, 0, stream>>>(row, col, bcnt, bucketbuf, e);
    bscan_kernel<<<1, 1024, 0, stream>>>(bcnt, bstart, NB);
    fill2_kernel<<<NB, 256, 0, stream>>>(bucketbuf, bcnt, bstart, offsets, dinv, csr_src, n, e);

    int n2 = n * 64;  // half2 count
    cast_kernel<<<(n2 + 255) / 256, 256, 0, stream>>>((const float2*)emb, xh, n2);

    const float* x = emb;
    for (int l = 0; l < NLAYERS; l++) {
        agg_kernel<<<n, 64, 0, stream>>>(xh, offsets, csr_src, dinv, aggbuf);
        gemm_bias_relu_kernel<<<n / 32, 256, 0, stream>>>(
            aggbuf, Ws + (size_t)l * D * D, bs + (size_t)l * D, out,
            xh, (l < NLAYERS - 1) ? 1 : 0);
    }
}

// Round 5
// 541.122 us; speedup vs baseline: 1.5145x; 1.0741x over previous
//
#include <hip/hip_runtime.h>
#include <hip/hip_fp16.h>
#include <cstdint>
#include <cstddef>

#define N_NODES 100000
#define N_EDGES 1600000
#define D 128
#define NLAYERS 3
#define NB 3125       // buckets of 32 nodes
#define NBLK_E 128    // edge-phase blocks
#define EPB 12500     // edges per block: 1600000/128
#define ENT_CAP 1024  // fill2 LDS entries; bucket max ~600 (22 sigma)

// ---------------- CSR build: LDS-histogram counting sort (no global atomics) ----------------

__global__ __launch_bounds__(512) void hist1_kernel(const int* __restrict__ col,
                                                    int* __restrict__ hmat) {
    __shared__ int hist[NB];
    int b = blockIdx.x, t = threadIdx.x;
    for (int j = t; j < NB; j += 512) hist[j] = 0;
    __syncthreads();
    int base = b * EPB;
    for (int i = t; i < EPB; i += 512) {
        int c = col[base + i];
        atomicAdd(&hist[c >> 5], 1);  // LDS atomic
    }
    __syncthreads();
    for (int j = t; j < NB; j += 512) hmat[b * NB + j] = hist[j];
}

__global__ void btot_kernel(const int* __restrict__ hmat, int* __restrict__ btot) {
    int j = blockIdx.x * 256 + threadIdx.x;
    if (j < NB) {
        int s = 0;
        for (int b = 0; b < NBLK_E; b++) s += hmat[b * NB + j];
        btot[j] = s;
    }
}

// Single-block exclusive scan over 3125 bucket totals -> bstart (+ sentinel).
__global__ void bscan_kernel(const int* __restrict__ btot, int* __restrict__ bstart, int nb, int e) {
    __shared__ int lsum[1024];
    int t = threadIdx.x;
    int vals[4];
    int v0 = 0;
#pragma unroll
    for (int j = 0; j < 4; j++) {
        int idx = t * 4 + j;
        int c = (idx < nb) ? btot[idx] : 0;
        vals[j] = c;
        v0 += c;
    }
    lsum[t] = v0;
    __syncthreads();
    for (int off = 1; off < 1024; off <<= 1) {
        int x = (t >= off) ? lsum[t - off] : 0;
        __syncthreads();
        lsum[t] += x;
        __syncthreads();
    }
    int base = lsum[t] - v0;  // exclusive
#pragma unroll
    for (int j = 0; j < 4; j++) {
        int idx = t * 4 + j;
        if (idx < nb) {
            bstart[idx] = base;
            base += vals[j];
        }
    }
    if (t == 0) bstart[nb] = e;
}

// Per-(block,bucket) start offsets: hoff[b][j] = bstart[j] + sum_{b'<b} hmat[b'][j]
__global__ void hoff_kernel(const int* __restrict__ hmat, const int* __restrict__ bstart,
                            int* __restrict__ hoff) {
    int j = blockIdx.x * 256 + threadIdx.x;
    if (j < NB) {
        int run = bstart[j];
        for (int b = 0; b < NBLK_E; b++) {
            hoff[b * NB + j] = run;
            run += hmat[b * NB + j];
        }
    }
}

// Scatter edges to exact bucket-sorted positions. LDS cursors, no global atomics.
__global__ __launch_bounds__(512) void scatter_kernel(const int* __restrict__ row,
                                                      const int* __restrict__ col,
                                                      const int* __restrict__ hoff,
                                                      unsigned* __restrict__ bucketbuf) {
    __shared__ int cur[NB];
    int b = blockIdx.x, t = threadIdx.x;
    for (int j = t; j < NB; j += 512) cur[j] = hoff[b * NB + j];
    __syncthreads();
    int base = b * EPB;
    for (int i = t; i < EPB; i += 512) {
        int r = row[base + i], c = col[base + i];
        int pos = atomicAdd(&cur[c >> 5], 1);  // LDS atomic
        bucketbuf[pos] = ((unsigned)r << 5) | (unsigned)(c & 31);
    }
}

// One block per bucket: LDS histogram of 32 local cols -> per-node offsets,
// dinv, and localized CSR scatter (contiguous ~2KB range, LDS cursors).
__global__ void fill2_kernel(const unsigned* __restrict__ bucketbuf, const int* __restrict__ bstart,
                             int* __restrict__ offsets, float* __restrict__ dinv,
                             int* __restrict__ src, int n, int e) {
    __shared__ unsigned ent[ENT_CAP];
    __shared__ int hist[32];
    __shared__ int cur[32];
    __shared__ int loff[32];
    int b = blockIdx.x, t = threadIdx.x;
    int s0 = bstart[b];
    int cnt = bstart[b + 1] - s0;
    if (cnt > ENT_CAP) cnt = ENT_CAP;
    if (t < 32) hist[t] = 0;
    __syncthreads();
    for (int i = t; i < cnt; i += 256) {
        unsigned v = bucketbuf[s0 + i];
        ent[i] = v;
        atomicAdd(&hist[v & 31], 1);
    }
    __syncthreads();
    if (t == 0) {
        int run = s0;
#pragma unroll
        for (int j = 0; j < 32; j++) {
            loff[j] = run;
            run += hist[j];
        }
    }
    __syncthreads();
    if (t < 32) {
        int node = b * 32 + t;
        int o = loff[t];
        offsets[node] = o;
        cur[t] = o;
        dinv[node] = rsqrtf((float)(hist[t] + 1));  // +1 self loop
    }
    if (b == 0 && t == 0) offsets[n] = e;
    __syncthreads();
    for (int i = t; i < cnt; i += 256) {
        unsigned v = ent[i];
        int pos = atomicAdd(&cur[v & 31], 1);
        src[pos] = (int)(v >> 5);
    }
}

// ---------------- per-layer kernels ----------------

// Cast fp32 features -> fp16 (halves gather traffic in agg).
__global__ void cast_kernel(const float2* __restrict__ in, __half2* __restrict__ out, int n2) {
    int i = blockIdx.x * 256 + threadIdx.x;
    if (i < n2) {
        float2 v = in[i];
        out[i] = __floats2half2_rn(v.x, v.y);
    }
}

// One 64-thread block per node; each thread owns a half2 feature pair.
// out[v] = dinv[v] * ( dinv[v]*x[v] + sum_e dinv[src_e]*x[src_e] ), fp32 accum.
__global__ void agg_kernel(const __half2* __restrict__ xh, const int* __restrict__ offs,
                           const int* __restrict__ src, const float* __restrict__ dinv,
                           float* __restrict__ out) {
    int v = blockIdx.x;
    int f = threadIdx.x;  // 0..63
    float dv = dinv[v];
    float2 xv = __half22float2(xh[(size_t)v * 64 + f]);
    float ax = dv * xv.x;
    float ay = dv * xv.y;
    int i = offs[v], s1 = offs[v + 1];
    for (; i + 3 < s1; i += 4) {
        int sA = src[i], sB = src[i + 1], sC = src[i + 2], sD = src[i + 3];
        float wA = dinv[sA], wB = dinv[sB], wC = dinv[sC], wD = dinv[sD];
        float2 xA = __half22float2(xh[(size_t)sA * 64 + f]);
        float2 xB = __half22float2(xh[(size_t)sB * 64 + f]);
        float2 xC = __half22float2(xh[(size_t)sC * 64 + f]);
        float2 xD = __half22float2(xh[(size_t)sD * 64 + f]);
        ax += xA.x * wA + xB.x * wB + xC.x * wC + xD.x * wD;
        ay += xA.y * wA + xB.y * wB + xC.y * wC + xD.y * wD;
    }
    for (; i < s1; i++) {
        int sA = src[i];
        float wA = dinv[sA];
        float2 xA = __half22float2(xh[(size_t)sA * 64 + f]);
        ax += xA.x * wA;
        ay += xA.y * wA;
    }
    float2 r;
    r.x = dv * ax;
    r.y = dv * ay;
    ((float2*)out)[(size_t)v * 64 + f] = r;
}

// out[M x 128] = relu(A[M x 128] @ W[128 x 128] + bias), 32 rows per block,
// W staged in LDS (64 KB), k-vectorized float4 inner loop (4 FLOP/LDS-byte).
// Optionally also writes an fp16 copy for the next layer's gather.
__global__ __launch_bounds__(256, 2) void gemm_bias_relu_kernel(
    const float* __restrict__ A, const float* __restrict__ W,
    const float* __restrict__ bias, float* __restrict__ out,
    __half2* __restrict__ xh_out, int write_h) {
    __shared__ float sW[128 * 128];  // 64 KB
    __shared__ float sX[32 * 128];   // 16 KB
    int t = threadIdx.x;
    int tx = t & 31;   // 32 col-groups of 4
    int ty = t >> 5;   // 8 row-groups of 4
    int row0 = blockIdx.x * 32;

    const float4* W4 = (const float4*)W;
    float4* sW4 = (float4*)sW;
#pragma unroll
    for (int i = 0; i < 16; i++) sW4[t + 256 * i] = W4[t + 256 * i];

    const float4* A4 = (const float4*)A;
    float4* sX4 = (float4*)sX;
#pragma unroll
    for (int i = 0; i < 4; i++) {
        int c = t + 256 * i;
        int r = c >> 5, kc = c & 31;
        sX4[r * 32 + kc] = A4[(size_t)(row0 + r) * 32 + kc];
    }
    __syncthreads();

    float4 acc[4];
#pragma unroll
    for (int r = 0; r < 4; r++) acc[r] = make_float4(0.f, 0.f, 0.f, 0.f);

#define FMA4(a, s, b) a.x += (s) * (b).x; a.y += (s) * (b).y; a.z += (s) * (b).z; a.w += (s) * (b).w;
#pragma unroll 4
    for (int k0 = 0; k0 < 128; k0 += 4) {
        float4 b0 = *(const float4*)&sW[(k0 + 0) * 128 + tx * 4];
        float4 b1 = *(const float4*)&sW[(k0 + 1) * 128 + tx * 4];
        float4 b2 = *(const float4*)&sW[(k0 + 2) * 128 + tx * 4];
        float4 b3 = *(const float4*)&sW[(k0 + 3) * 128 + tx * 4];
#pragma unroll
        for (int r = 0; r < 4; r++) {
            float4 a = *(const float4*)&sX[(ty * 4 + r) * 128 + k0];
            FMA4(acc[r], a.x, b0)
            FMA4(acc[r], a.y, b1)
            FMA4(acc[r], a.z, b2)
            FMA4(acc[r], a.w, b3)
        }
    }
#undef FMA4

    float4 bb = ((const float4*)bias)[tx];
#pragma unroll
    for (int r = 0; r < 4; r++) {
        float4 o;
        o.x = fmaxf(acc[r].x + bb.x, 0.0f);
        o.y = fmaxf(acc[r].y + bb.y, 0.0f);
        o.z = fmaxf(acc[r].z + bb.z, 0.0f);
        o.w = fmaxf(acc[r].w + bb.w, 0.0f);
        size_t rowi = (size_t)(row0 + ty * 4 + r);
        ((float4*)out)[rowi * 32 + tx] = o;
        if (write_h) {
            xh_out[rowi * 64 + tx * 2] = __floats2half2_rn(o.x, o.y);
            xh_out[rowi * 64 + tx * 2 + 1] = __floats2half2_rn(o.z, o.w);
        }
    }
}

// ---------------- launch ----------------

extern "C" void kernel_launch(void* const* d_in, const int* in_sizes, int n_in,
                              void* d_out, int out_size, void* d_ws, size_t ws_size,
                              hipStream_t stream) {
    const int* edge = (const int*)d_in[0];   // [2, E] int32
    const float* emb = (const float*)d_in[1];
    const float* Ws = (const float*)d_in[2]; // [L, D, D]
    const float* bs = (const float*)d_in[3]; // [L, D]
    float* out = (float*)d_out;

    const int n = N_NODES, e = N_EDGES;
    const int* row = edge;       // sources
    const int* col = edge + e;   // targets

    char* p = (char*)d_ws;
    float* aggbuf = (float*)p;
    int* hmat = (int*)p;                      // aliases aggbuf (dead until first agg)
    int* hoff = hmat + (size_t)NBLK_E * NB;
    p += (size_t)n * D * 4;                   // 51.2 MB
    __half2* xh = (__half2*)p;                // 25.6 MB
    unsigned* bucketbuf = (unsigned*)p;       // aliases xh: dead before cast runs
    p += (size_t)n * D * 2;
    int* csr_src  = (int*)p;    p += (size_t)e * 4;           // 6.4 MB
    float* dinv   = (float*)p;  p += (size_t)n * 4;
    int* offsets  = (int*)p;    p += (size_t)(n + 1) * 4;
    int* btot     = (int*)p;    p += (size_t)NB * 4;
    int* bstart   = (int*)p;    p += (size_t)(NB + 1) * 4;

    hist1_kernel<<<NBLK_E, 512, 0, stream>>>(col, hmat);
    btot_kernel<<<(NB + 255) / 256, 256, 0, stream>>>(hmat, btot);
    bscan_kernel<<<1, 1024, 0, stream>>>(btot, bstart, NB, e);
    hoff_kernel<<<(NB + 255) / 256, 256, 0, stream>>>(hmat, bstart, hoff);
    scatter_kernel<<<NBLK_E, 512, 0, stream>>>(row, col, hoff, bucketbuf);
    fill2_kernel<<<NB, 256, 0, stream>>>(bucketbuf, bstart, offsets, dinv, csr_src, n, e);

    int n2 = n * 64;  // half2 count
    cast_kernel<<<(n2 + 255) / 256, 256, 0, stream>>>((const float2*)emb, xh, n2);

    for (int l = 0; l < NLAYERS; l++) {
        agg_kernel<<<n, 64, 0, stream>>>(xh, offsets, csr_src, dinv, aggbuf);
        gemm_bias_relu_kernel<<<n / 32, 256, 0, stream>>>(
            aggbuf, Ws + (size_t)l * D * D, bs + (size_t)l * D, out,
            xh, (l < NLAYERS - 1) ? 1 : 0);
    }
}